// Round 12
// baseline (118.439 us; speedup 1.0000x reference)
//
#include <hip/hip_runtime.h>
#include <math.h>

#define NQ    8192
#define NPTS  32768
#define KNN   64
#define CAP   256            // per-query candidate capacity (4 regs/lane select)
#define PG    64             // point-grid cells per dim (cell 0.15)
#define PNC   (PG*PG*PG)     // 262144
#define PCELL 0.15f
#define PGINV (PG / 9.6f)
#define QG    32             // query-sort grid (locality only)
#define QNC   (QG*QG*QG)     // 32768
#define QGINV (QG / 9.6f)
#define GLO   (-4.8f)
#define NBLK  2048           // main grid: 4 queries (waves) per block
#define TGT   (110.0f / 32768.0f)  // E[cand]=110: P(<64) ~ 5e-6/query, P(>256) ~ 0
#define PCHUNKS (PNC / 1024)  // 256
#define QCHUNKS (QNC / 1024)  // 32

// ---- order-preserving float<->uint key ----
__device__ __forceinline__ unsigned key_of(float f) {
  unsigned u = __float_as_uint(f);
  return (u & 0x80000000u) ? ~u : (u | 0x80000000u);
}
__device__ __forceinline__ float val_of(unsigned k) {
  unsigned u = (k & 0x80000000u) ? (k & 0x7fffffffu) : ~k;
  return __uint_as_float(u);
}
__device__ __forceinline__ int mbcnt64(unsigned long long m) {
  return __builtin_amdgcn_mbcnt_hi((unsigned)(m >> 32),
         __builtin_amdgcn_mbcnt_lo((unsigned)m, 0));
}
__device__ __forceinline__ float rflf(float x) {
  return __int_as_float(__builtin_amdgcn_readfirstlane(__float_as_int(x)));
}
__device__ __forceinline__ int rfli(int x) { return __builtin_amdgcn_readfirstlane(x); }

__device__ __forceinline__ float norm_cdf(float x) { return 0.5f * erfcf(-x * 0.70710678f); }
// Mass of standard 3D gaussian inside ball radius r centered at distance mu.
__device__ __forceinline__ float ball_mass(float mu, float r) {
  float a = r - mu, b = r + mu;
  float e = __expf(-0.5f * b * b) - __expf(-0.5f * a * a);
  return e / (mu * 2.50662827f) + norm_cdf(a) - norm_cdf(-mu) + norm_cdf(b) - norm_cdf(mu);
}

__device__ __forceinline__ int cidxP(float v) {
  int i = (int)floorf((v - GLO) * PGINV);
  return min(max(i, 0), PG - 1);
}
__device__ __forceinline__ int cidxQ(float v) {
  int i = (int)floorf((v - GLO) * QGINV);
  return min(max(i, 0), QG - 1);
}

// ================= preprocessing: parallel multi-kernel =================
// counters + publish flags zeroed by hipMemsetAsync before hist_tau_kernel

__global__ __launch_bounds__(256) void hist_tau_kernel(
    const float* __restrict__ pos, const float* __restrict__ qpos,
    int* __restrict__ pcnt, int* __restrict__ qcnt, float* __restrict__ tau) {
  const int gid = blockIdx.x * 256 + threadIdx.x;          // 32768 threads
  const float x = pos[gid * 3 + 0], y = pos[gid * 3 + 1], z = pos[gid * 3 + 2];
  atomicAdd(&pcnt[(cidxP(z) * PG + cidxP(y)) * PG + cidxP(x)], 1);
  if (gid < NQ) {
    const float qx = qpos[gid * 3 + 0], qy = qpos[gid * 3 + 1], qz = qpos[gid * 3 + 2];
    atomicAdd(&qcnt[(cidxQ(qz) * QG + cidxQ(qy)) * QG + cidxQ(qx)], 1);
    // robust tau: 16-iter bisection of exact ball mass (device-parallel here)
    const float b = qx * qx + qy * qy + qz * qz;
    const float mu = fmaxf(sqrtf(b), 0.05f);
    float lo = 0.f, hi = mu + 8.f;
    for (int i = 0; i < 16; ++i) {
      const float r = 0.5f * (lo + hi);
      if (ball_mass(mu, r) < TGT) lo = r; else hi = r;
    }
    tau[gid] = hi * hi;
  }
}

// Single-dispatch chunked scan with decoupled lookback.
// blocks [0,256): point chunks -> final cellStart + pcnt cursor
// blocks [256,288): query chunks -> final qcnt cursor (in place)
// Deadlock-free: all 288 blocks co-resident (<=2048 capacity) and every block
// publishes BEFORE it spins, so lookback on earlier chunks always terminates.
// Only atomics cross blocks (device-scope coherent) -- no plain-load races.
__global__ __launch_bounds__(256) void scan_kernel(
    int* __restrict__ pcnt, int* __restrict__ qcnt, int* __restrict__ cellStart,
    int* __restrict__ ppub, int* __restrict__ qpub) {
  __shared__ int aux[256];   // local inclusive prefix of per-thread sums
  __shared__ int off[256];   // lookback reduction scratch
  const int t = threadIdx.x;
  const bool isP = (blockIdx.x < PCHUNKS);
  const int cb = isP ? blockIdx.x : (blockIdx.x - PCHUNKS);
  int* src = isP ? pcnt : qcnt;
  int* pub = isP ? ppub : qpub;
  const int base = cb * 1024 + t * 4;
  const int4 q = ((const int4*)(src + base))[0];
  aux[t] = q.x + q.y + q.z + q.w;
  __syncthreads();
  for (int o = 1; o < 256; o <<= 1) {
    const int u = (t >= o) ? aux[t - o] : 0;
    __syncthreads();
    aux[t] += u;
    __syncthreads();
  }
  // publish chunk total (+1 sentinel: zero-total chunks still publish nonzero)
  if (t == 0) atomicExch(&pub[cb], aux[255] + 1);
  // lookback: thread t spins on chunk t's published total (t < cb)
  int v = 0;
  if (t < cb) {
    while ((v = atomicOr(&pub[t], 0)) == 0) { }
    v -= 1;
  }
  off[t] = v;
  __syncthreads();
  for (int o = 128; o; o >>= 1) {
    if (t < o) off[t] += off[t + o];
    __syncthreads();
  }
  const int chunkOff = off[0];
  // final offset-adjusted exclusive prefix, written once
  int run = (t ? aux[t - 1] : 0) + chunkOff;
  int4 w;
  w.x = run; run += q.x;
  w.y = run; run += q.y;
  w.z = run; run += q.z;
  w.w = run; run += q.w;
  if (isP) {
    ((int4*)(cellStart + base))[0] = w;   // persistent starts for knn
    ((int4*)(pcnt + base))[0] = w;        // scatter cursor
    if (cb == PCHUNKS - 1 && t == 255) cellStart[PNC] = NPTS;
  } else {
    ((int4*)(qcnt + base))[0] = w;        // query scatter cursor
  }
}

__global__ __launch_bounds__(256) void scatter_kernel(
    const float* __restrict__ pos, const float* __restrict__ qpos,
    int* __restrict__ pcur, int* __restrict__ qcur, const float* __restrict__ tau,
    float4* __restrict__ pts, float4* __restrict__ qp, float* __restrict__ qtau) {
  const int gid = blockIdx.x * 256 + threadIdx.x;
  const float x = pos[gid * 3 + 0], y = pos[gid * 3 + 1], z = pos[gid * 3 + 2];
  const int c = (cidxP(z) * PG + cidxP(y)) * PG + cidxP(x);
  const int slot = atomicAdd(&pcur[c], 1);
  pts[slot] = make_float4(x, y, z, __int_as_float(gid));
  if (gid < NQ) {
    const float a = qpos[gid * 3 + 0], b = qpos[gid * 3 + 1], d = qpos[gid * 3 + 2];
    const int qc = (cidxQ(d) * QG + cidxQ(b)) * QG + cidxQ(a);
    const int qs = atomicAdd(&qcur[qc], 1);
    qp[qs] = make_float4(a, b, d, __int_as_float(gid));
    qtau[qs] = tau[gid];
  }
}

// ================= main: one wave per (spatially sorted) query =================

__global__ __launch_bounds__(256, 8) void knn_main(
    const float* __restrict__ feat, const int* __restrict__ cellStart,
    const float4* __restrict__ pts, const float4* __restrict__ qp,
    const float* __restrict__ qtau, float* __restrict__ out) {

  __shared__ uint2 sCand[4][CAP];   // per-wave candidate buffer (key, point idx)
  __shared__ uint2 sSel[4][KNN];    // (idx, weight bits)

  const int tid = threadIdx.x, lane = tid & 63, wv = tid >> 6;
  // XCD swizzle: 256 consecutive blocks (1024 spatially-adjacent queries) per XCD
  const int bid = blockIdx.x;
  const int swz = (bid & 7) * (NBLK / 8) + (bid >> 3);
  const int sq  = swz * 4 + wv;

  const float4 Q = qp[sq];
  const float qx = rflf(Q.x), qy = rflf(Q.y), qz = rflf(Q.z);
  const int orig = rfli(__float_as_int(Q.w));
  const float bq = qx * qx + qy * qy + qz * qz;
  const float nx = -2.f * qx, ny = -2.f * qy, nz = -2.f * qz;
  float r2 = rflf(qtau[sq]);
  float tlo = 0.f, thi = -1.f;
  int cnt = 0;

  // ---- candidate scan: 64-row rounds over the fine (0.15) grid ----
  for (int attempt = 0; attempt < 12; ++attempt) {
    const float r = sqrtf(r2);
    const float tq = r2 - bq;        // d' = |p|^2 - 2 q.p  vs  tau - |q|^2
    const int iy0 = cidxP(qy - r), iy1 = cidxP(qy + r);
    const int iz0 = cidxP(qz - r), iz1 = cidxP(qz + r);
    const int nyw  = iy1 - iy0 + 1;
    const int nrow = nyw * (iz1 - iz0 + 1);
    cnt = 0;
    for (int rc = 0; rc < nrow; rc += 64) {
      // all 64 lanes fetch one row each, culled by ball distance in (y,z)
      const int myrow = rc + lane;
      int s = 0, c = 0;
      if (myrow < nrow) {
        const int dz = myrow / nyw;            // nyw in [1,64]
        const int dy = myrow - dz * nyw;
        const int giy = iy0 + dy, giz = iz0 + dz;
        const float ylo = GLO + giy * PCELL;
        const float zlo = GLO + giz * PCELL;
        const float dyv = fmaxf(0.f, fmaxf(ylo - qy, qy - (ylo + PCELL)));
        const float dzv = fmaxf(0.f, fmaxf(zlo - qz, qz - (zlo + PCELL)));
        const float dd = dyv * dyv + dzv * dzv;
        if (dd < r2) {                         // row intersects the ball
          const float hx = sqrtf(r2 - dd);     // safe x half-width for this row
          const int jx0 = cidxP(qx - hx), jx1 = cidxP(qx + hx);
          const int rb = (giz * PG + giy) * PG;
          s = cellStart[rb + jx0];
          c = cellStart[rb + jx1 + 1] - s;     // x-run contiguous in sorted pts
        }
      }
      int cum = c;                             // 6-step scan over 64 lanes
      #pragma unroll
      for (int off = 1; off < 64; off <<= 1) {
        const int u = __shfl_up(cum, off);
        if (lane >= off) cum += u;
      }
      const int adj = s - (cum - c);           // row flat-base adjustment
      const int Tc = __shfl(cum, 63);
      // flattened scan: row lookup = 6-step bpermute binary search over 64 rows
      for (int b = 0; b < Tc; b += 64) {
        const int fi = b + lane;
        const bool have = fi < Tc;
        int ro = 0;                            // ro = #{j: cum[j] <= fi}
        #pragma unroll
        for (int st = 32; st; st >>= 1) {
          const int nr = ro + st;
          const int probe = __shfl(cum, min(nr, 64) - 1);
          if (nr <= 64 && probe <= fi) ro = nr;
        }
        const int pi = fi + __shfl(adj, min(ro, 63));
        const float4 P = pts[have ? pi : 0];
        const float n = P.x * P.x + P.y * P.y + P.z * P.z;
        const float d = fmaf(P.z, nz, fmaf(P.y, ny, fmaf(P.x, nx, n)));
        const bool hh = have && (d < tq);
        const unsigned long long m = __ballot(hh);
        if (m) {
          const int p = cnt + mbcnt64(m);
          if (hh && p < CAP)
            sCand[wv][p] = make_uint2(key_of(d + bq), __float_as_uint(P.w));
          cnt += (int)__popcll(m);
        }
      }
    }
    if (cnt >= KNN && cnt <= CAP) break;
    if (cnt < KNN) { tlo = r2; r2 = (thi < 0.f) ? r2 * 3.f : 0.5f * (r2 + thi); }
    else           { thi = r2; r2 = 0.5f * (tlo + r2); }
  }

  // ---- exact top-64 select within the wave ----
  {
    const int mm = min(cnt, CAP);
    unsigned k[4], id[4];
    #pragma unroll
    for (int s = 0; s < 4; ++s) {
      const int g2 = s * 64 + lane;
      uint2 kv = make_uint2(0xFFFFFFFFu, 0u);
      if (g2 < mm) kv = sCand[wv][g2];
      k[s] = kv.x; id[s] = kv.y;
    }
    // keys of d^2 >= 0 always have the top bit set -> start blo there
    unsigned blo = 0x80000000u, bhi = 0xFFFFFFFFu;   // bisect exact 64th-smallest key
    for (int it = 0; it < 32; ++it) {
      const unsigned mid = blo + ((bhi - blo) >> 1);
      const int c = (int)(__popcll(__ballot(k[0] <= mid)) + __popcll(__ballot(k[1] <= mid)) +
                          __popcll(__ballot(k[2] <= mid)) + __popcll(__ballot(k[3] <= mid)));
      if (c >= KNN) bhi = mid; else blo = mid + 1;
    }
    const unsigned K = blo;

    int fill = 0;
    #pragma unroll
    for (int s = 0; s < 4; ++s) {
      const bool lt = k[s] < K;
      const unsigned long long msk = __ballot(lt);
      if (msk) {
        const int p = fill + mbcnt64(msk);
        if (lt) { const float dv = val_of(k[s]);
                  const float w_ = 1.f / (sqrtf(fmaxf(dv, 1e-12f)) + 1e-5f);
                  sSel[wv][p] = make_uint2(id[s], __float_as_uint(w_)); }
        fill += (int)__popcll(msk);
      }
    }
    #pragma unroll
    for (int s = 0; s < 4; ++s) {          // ties at K fill remaining slots
      const bool eq = (k[s] == K);
      const unsigned long long msk = __ballot(eq);
      if (msk) {
        const int p = fill + mbcnt64(msk);
        if (eq && p < KNN) { const float dv = val_of(k[s]);
                             const float w_ = 1.f / (sqrtf(fmaxf(dv, 1e-12f)) + 1e-5f);
                             sSel[wv][p] = make_uint2(id[s], __float_as_uint(w_)); }
        fill += (int)__popcll(msk);
      }
    }
  }

  // ---- gather: float4/lane, halves split even/odd neighbors, 32 iterations ----
  {
    const int half = lane >> 5;            // 0: even j, 1: odd j
    const int col  = lane & 31;            // float4 column
    float4 acc = make_float4(0.f, 0.f, 0.f, 0.f);
    #pragma unroll 4
    for (int j = 0; j < KNN; j += 2) {
      const uint2 pr = sSel[wv][j + half];     // broadcast LDS read per half
      const float w = __uint_as_float(pr.y);
      const float4 f4 = *(const float4*)(feat + ((size_t)pr.x << 7) + (col << 2));
      acc.x = fmaf(w, f4.x, acc.x);
      acc.y = fmaf(w, f4.y, acc.y);
      acc.z = fmaf(w, f4.z, acc.z);
      acc.w = fmaf(w, f4.w, acc.w);
    }
    acc.x += __shfl_xor(acc.x, 32);
    acc.y += __shfl_xor(acc.y, 32);
    acc.z += __shfl_xor(acc.z, 32);
    acc.w += __shfl_xor(acc.w, 32);
    if (lane < 32)
      *(float4*)(out + ((size_t)orig << 7) + (col << 2)) = acc;
  }
}

extern "C" void kernel_launch(void* const* d_in, const int* in_sizes, int n_in,
                              void* d_out, int out_size, void* d_ws, size_t ws_size,
                              hipStream_t stream) {
  const float* qpos = (const float*)d_in[0];   // [8192,3]
  const float* feat = (const float*)d_in[1];   // [32768,128]
  const float* pos  = (const float*)d_in[2];   // [32768,3]
  float* out = (float*)d_out;                  // [8192,128]

  char* ws = (char*)d_ws;
  int*    pcnt      = (int*)(ws);                      // 1 MB   (point hist -> cursor)
  int*    qcnt      = (int*)(ws + (1024 << 10));       // 128 KB (query hist -> cursor)
  int*    ppub      = (int*)(ws + (1152 << 10));       // 1 KB (point chunk totals+1)
  int*    qpub      = (int*)(ws + (1153 << 10));       // 128 B (query chunk totals+1)
  int*    cellStart = (int*)(ws + (1156 << 10));       // 1 MB + 4 B (262145 ints)
  float*  tau       = (float*)(ws + (2188 << 10));     // 32 KB (by orig query idx)
  float4* pts       = (float4*)(ws + (2220 << 10));    // 512 KB (sorted points)
  float4* qp        = (float4*)(ws + (2732 << 10));    // 128 KB (sorted queries)
  float*  qtau      = (float*)(ws + (2860 << 10));     // 32 KB (sorted tau)

  hipMemsetAsync(ws, 0, 1154 << 10, stream);           // zero hists + publish flags
  hist_tau_kernel<<<dim3(NPTS / 256),        dim3(256), 0, stream>>>(pos, qpos, pcnt, qcnt, tau);
  scan_kernel    <<<dim3(PCHUNKS + QCHUNKS), dim3(256), 0, stream>>>(pcnt, qcnt, cellStart, ppub, qpub);
  scatter_kernel <<<dim3(NPTS / 256),        dim3(256), 0, stream>>>(pos, qpos, pcnt, qcnt, tau, pts, qp, qtau);
  knn_main       <<<dim3(NBLK),              dim3(256), 0, stream>>>(feat, cellStart, pts, qp, qtau, out);
}

// Round 13
// 115.719 us; speedup vs baseline: 1.0235x; 1.0235x over previous
//
#include <hip/hip_runtime.h>
#include <math.h>

#define NQ    8192
#define NPTS  32768
#define KNN   64
#define CAP   256            // per-query candidate capacity (4 regs/lane select)
#define RCAP  256            // per-wave compacted-row buffer entries
#define PG    64             // point-grid cells per dim (cell 0.15)
#define PNC   (PG*PG*PG)     // 262144
#define PCELL 0.15f
#define PGINV (PG / 9.6f)
#define QG    32             // query-sort grid (locality only)
#define QNC   (QG*QG*QG)     // 32768
#define QGINV (QG / 9.6f)
#define GLO   (-4.8f)
#define NBLK  2048           // main grid: 4 queries (waves) per block
#define TGT   (110.0f / 32768.0f)  // E[cand]=110: P(<64) ~ 5e-6/query, P(>256) ~ 0
#define PCHUNKS (PNC / 1024)  // 256
#define QCHUNKS (QNC / 1024)  // 32

// ---- order-preserving float<->uint key ----
__device__ __forceinline__ unsigned key_of(float f) {
  unsigned u = __float_as_uint(f);
  return (u & 0x80000000u) ? ~u : (u | 0x80000000u);
}
__device__ __forceinline__ float val_of(unsigned k) {
  unsigned u = (k & 0x80000000u) ? (k & 0x7fffffffu) : ~k;
  return __uint_as_float(u);
}
__device__ __forceinline__ int mbcnt64(unsigned long long m) {
  return __builtin_amdgcn_mbcnt_hi((unsigned)(m >> 32),
         __builtin_amdgcn_mbcnt_lo((unsigned)m, 0));
}
__device__ __forceinline__ float rflf(float x) {
  return __int_as_float(__builtin_amdgcn_readfirstlane(__float_as_int(x)));
}
__device__ __forceinline__ int rfli(int x) { return __builtin_amdgcn_readfirstlane(x); }

__device__ __forceinline__ float norm_cdf(float x) { return 0.5f * erfcf(-x * 0.70710678f); }
// Mass of standard 3D gaussian inside ball radius r centered at distance mu.
__device__ __forceinline__ float ball_mass(float mu, float r) {
  float a = r - mu, b = r + mu;
  float e = __expf(-0.5f * b * b) - __expf(-0.5f * a * a);
  return e / (mu * 2.50662827f) + norm_cdf(a) - norm_cdf(-mu) + norm_cdf(b) - norm_cdf(mu);
}

__device__ __forceinline__ int cidxP(float v) {
  int i = (int)floorf((v - GLO) * PGINV);
  return min(max(i, 0), PG - 1);
}
__device__ __forceinline__ int cidxQ(float v) {
  int i = (int)floorf((v - GLO) * QGINV);
  return min(max(i, 0), QG - 1);
}

// ================= preprocessing: parallel multi-kernel =================
// counters + publish flags zeroed by hipMemsetAsync before hist_tau_kernel

__global__ __launch_bounds__(256) void hist_tau_kernel(
    const float* __restrict__ pos, const float* __restrict__ qpos,
    int* __restrict__ pcnt, int* __restrict__ qcnt, float* __restrict__ tau) {
  const int gid = blockIdx.x * 256 + threadIdx.x;          // 32768 threads
  const float x = pos[gid * 3 + 0], y = pos[gid * 3 + 1], z = pos[gid * 3 + 2];
  atomicAdd(&pcnt[(cidxP(z) * PG + cidxP(y)) * PG + cidxP(x)], 1);
  if (gid < NQ) {
    const float qx = qpos[gid * 3 + 0], qy = qpos[gid * 3 + 1], qz = qpos[gid * 3 + 2];
    atomicAdd(&qcnt[(cidxQ(qz) * QG + cidxQ(qy)) * QG + cidxQ(qx)], 1);
    // robust tau: 16-iter bisection of exact ball mass (device-parallel here)
    const float b = qx * qx + qy * qy + qz * qz;
    const float mu = fmaxf(sqrtf(b), 0.05f);
    float lo = 0.f, hi = mu + 8.f;
    for (int i = 0; i < 16; ++i) {
      const float r = 0.5f * (lo + hi);
      if (ball_mass(mu, r) < TGT) lo = r; else hi = r;
    }
    tau[gid] = hi * hi;
  }
}

// Single-dispatch chunked scan with decoupled lookback (validated round 12).
__global__ __launch_bounds__(256) void scan_kernel(
    int* __restrict__ pcnt, int* __restrict__ qcnt, int* __restrict__ cellStart,
    int* __restrict__ ppub, int* __restrict__ qpub) {
  __shared__ int aux[256];   // local inclusive prefix of per-thread sums
  __shared__ int off[256];   // lookback reduction scratch
  const int t = threadIdx.x;
  const bool isP = (blockIdx.x < PCHUNKS);
  const int cb = isP ? blockIdx.x : (blockIdx.x - PCHUNKS);
  int* src = isP ? pcnt : qcnt;
  int* pub = isP ? ppub : qpub;
  const int base = cb * 1024 + t * 4;
  const int4 q = ((const int4*)(src + base))[0];
  aux[t] = q.x + q.y + q.z + q.w;
  __syncthreads();
  for (int o = 1; o < 256; o <<= 1) {
    const int u = (t >= o) ? aux[t - o] : 0;
    __syncthreads();
    aux[t] += u;
    __syncthreads();
  }
  if (t == 0) atomicExch(&pub[cb], aux[255] + 1);   // publish total (+1 sentinel)
  int v = 0;
  if (t < cb) {                                     // lookback spin
    while ((v = atomicOr(&pub[t], 0)) == 0) { }
    v -= 1;
  }
  off[t] = v;
  __syncthreads();
  for (int o = 128; o; o >>= 1) {
    if (t < o) off[t] += off[t + o];
    __syncthreads();
  }
  const int chunkOff = off[0];
  int run = (t ? aux[t - 1] : 0) + chunkOff;
  int4 w;
  w.x = run; run += q.x;
  w.y = run; run += q.y;
  w.z = run; run += q.z;
  w.w = run; run += q.w;
  if (isP) {
    ((int4*)(cellStart + base))[0] = w;   // persistent starts for knn
    ((int4*)(pcnt + base))[0] = w;        // scatter cursor
    if (cb == PCHUNKS - 1 && t == 255) cellStart[PNC] = NPTS;
  } else {
    ((int4*)(qcnt + base))[0] = w;        // query scatter cursor
  }
}

__global__ __launch_bounds__(256) void scatter_kernel(
    const float* __restrict__ pos, const float* __restrict__ qpos,
    int* __restrict__ pcur, int* __restrict__ qcur, const float* __restrict__ tau,
    float4* __restrict__ pts, float4* __restrict__ qp, float* __restrict__ qtau) {
  const int gid = blockIdx.x * 256 + threadIdx.x;
  const float x = pos[gid * 3 + 0], y = pos[gid * 3 + 1], z = pos[gid * 3 + 2];
  const int c = (cidxP(z) * PG + cidxP(y)) * PG + cidxP(x);
  const int slot = atomicAdd(&pcur[c], 1);
  pts[slot] = make_float4(x, y, z, __int_as_float(gid));
  if (gid < NQ) {
    const float a = qpos[gid * 3 + 0], b = qpos[gid * 3 + 1], d = qpos[gid * 3 + 2];
    const int qc = (cidxQ(d) * QG + cidxQ(b)) * QG + cidxQ(a);
    const int qs = atomicAdd(&qcur[qc], 1);
    qp[qs] = make_float4(a, b, d, __int_as_float(gid));
    qtau[qs] = tau[gid];
  }
}

// ================= main: one wave per (spatially sorted) query =================

__global__ __launch_bounds__(256, 8) void knn_main(
    const float* __restrict__ feat, const int* __restrict__ cellStart,
    const float4* __restrict__ pts, const float4* __restrict__ qp,
    const float* __restrict__ qtau, float* __restrict__ out) {

  __shared__ uint2 sCand[4][CAP];   // per-wave candidate buffer (key, point idx)
  __shared__ uint2 sSel[4][KNN];    // (idx, weight bits)
  __shared__ int   sRC[4][RCAP];    // compacted rows: inclusive cum point count
  __shared__ int   sAdj[4][RCAP];   // compacted rows: start - cumStart

  const int tid = threadIdx.x, lane = tid & 63, wv = tid >> 6;
  // XCD swizzle: 256 consecutive blocks (1024 spatially-adjacent queries) per XCD
  const int bid = blockIdx.x;
  const int swz = (bid & 7) * (NBLK / 8) + (bid >> 3);
  const int sq  = swz * 4 + wv;

  const float4 Q = qp[sq];
  const float qx = rflf(Q.x), qy = rflf(Q.y), qz = rflf(Q.z);
  const int orig = rfli(__float_as_int(Q.w));
  const float bq = qx * qx + qy * qy + qz * qz;
  const float nx = -2.f * qx, ny = -2.f * qy, nz = -2.f * qz;
  float r2 = rflf(qtau[sq]);
  float tlo = 0.f, thi = -1.f;
  int cnt = 0;

  // ---- candidate scan: pipelined bound-fetch + row compaction, then flat drain ----
  for (int attempt = 0; attempt < 12; ++attempt) {
    const float r = sqrtf(r2);
    const float tq = r2 - bq;        // d' = |p|^2 - 2 q.p  vs  tau - |q|^2
    const int iy0 = cidxP(qy - r), iy1 = cidxP(qy + r);
    const int iz0 = cidxP(qz - r), iz1 = cidxP(qz + r);
    const int nyw  = iy1 - iy0 + 1;
    const int nrow = nyw * (iz1 - iz0 + 1);
    cnt = 0;
    int nbuf = 0, tot = 0;

    // evaluate one 64-point batch of the drain (common candidate test)
    auto probe_pt = [&](int pi, bool have) {
      const float4 P = pts[have ? pi : 0];
      const float n = P.x * P.x + P.y * P.y + P.z * P.z;
      const float d = fmaf(P.z, nz, fmaf(P.y, ny, fmaf(P.x, nx, n)));
      const bool hh = have && (d < tq);
      const unsigned long long m = __ballot(hh);
      if (m) {
        const int p = cnt + mbcnt64(m);
        if (hh && p < CAP)
          sCand[wv][p] = make_uint2(key_of(d + bq), __float_as_uint(P.w));
        cnt += (int)__popcll(m);
      }
    };

    // drain the compacted row buffer: flat point scan over tot points
    auto drain = [&]() {
      if (nbuf == 0) return;
      if (nbuf <= 64) {                       // common case: rows fit in registers
        const int rcv = (lane < nbuf) ? sRC[wv][lane] : 0x7FFFFFFF;
        const int adv = (lane < nbuf) ? sAdj[wv][lane] : 0;
        for (int b = 0; b < tot; b += 64) {
          const int fi = b + lane;
          const bool have = fi < tot;
          int ro = 0;                         // ro = #{j: cumEnd[j] <= fi}
          #pragma unroll
          for (int st = 32; st; st >>= 1) {
            const int nr = ro + st;
            const int probe = __shfl(rcv, min(nr, nbuf) - 1);
            if (nr <= nbuf && probe <= fi) ro = nr;
          }
          const int pi = fi + __shfl(adv, min(ro, nbuf - 1));
          probe_pt(pi, have);
        }
      } else {                                // tail case: LDS binary search
        for (int b = 0; b < tot; b += 64) {
          const int fi = b + lane;
          const bool have = fi < tot;
          int ro = 0;
          #pragma unroll
          for (int st = 128; st; st >>= 1) {
            const int nr = ro + st;
            if (nr <= nbuf && sRC[wv][nr - 1] <= fi) ro = nr;
          }
          const int pi = fi + sAdj[wv][min(ro, nbuf - 1)];
          probe_pt(pi, have);
        }
      }
      nbuf = 0; tot = 0;
    };

    // issue bound loads for one 64-row round (values consumed one round later)
    auto issue = [&](int rcb, int& sR, int& eR, bool& vd) {
      vd = false; sR = 0; eR = 0;
      const int myrow = rcb + lane;
      if (myrow < nrow) {
        const int dz = myrow / nyw;            // nyw in [1,64]
        const int dy = myrow - dz * nyw;
        const int giy = iy0 + dy, giz = iz0 + dz;
        const float ylo = GLO + giy * PCELL;
        const float zlo = GLO + giz * PCELL;
        const float dyv = fmaxf(0.f, fmaxf(ylo - qy, qy - (ylo + PCELL)));
        const float dzv = fmaxf(0.f, fmaxf(zlo - qz, qz - (zlo + PCELL)));
        const float dd = dyv * dyv + dzv * dzv;
        if (dd < r2) {                         // row intersects the ball
          const float hx = sqrtf(r2 - dd);     // safe x half-width for this row
          const int jx0 = cidxP(qx - hx), jx1 = cidxP(qx + hx);
          const int rb = (giz * PG + giy) * PG;
          sR = cellStart[rb + jx0];
          eR = cellStart[rb + jx1 + 1];        // x-run contiguous in sorted pts
          vd = true;
        }
      }
    };

    int sR0 = 0, eR0 = 0; bool v0 = false;
    issue(0, sR0, eR0, v0);                    // prologue
    for (int rc = 0; rc < nrow; rc += 64) {
      int sR1 = 0, eR1 = 0; bool v1 = false;
      if (rc + 64 < nrow) issue(rc + 64, sR1, eR1, v1);   // prefetch next round
      // consume current round: compact non-empty rows into the buffer
      const int c = v0 ? (eR0 - sR0) : 0;
      const int s = v0 ? sR0 : 0;
      int cum = c;                             // 6-step inclusive prefix over 64 lanes
      #pragma unroll
      for (int off = 1; off < 64; off <<= 1) {
        const int u = __shfl_up(cum, off);
        if (lane >= off) cum += u;
      }
      const unsigned long long act = __ballot(c > 0);
      const int slot = nbuf + mbcnt64(act);
      if (c > 0) {
        sRC[wv][slot]  = tot + cum;            // inclusive end (buffer-relative)
        sAdj[wv][slot] = s - (tot + cum - c);  // start - cumStart
      }
      nbuf += (int)__popcll(act);
      tot  += __shfl(cum, 63);
      if (nbuf > RCAP - 64) drain();           // rare: keep room for next round
      sR0 = sR1; eR0 = eR1; v0 = v1;
    }
    drain();

    if (cnt >= KNN && cnt <= CAP) break;
    if (cnt < KNN) { tlo = r2; r2 = (thi < 0.f) ? r2 * 3.f : 0.5f * (r2 + thi); }
    else           { thi = r2; r2 = 0.5f * (tlo + r2); }
  }

  // ---- exact top-64 select within the wave ----
  {
    const int mm = min(cnt, CAP);
    unsigned k[4], id[4];
    #pragma unroll
    for (int s = 0; s < 4; ++s) {
      const int g2 = s * 64 + lane;
      uint2 kv = make_uint2(0xFFFFFFFFu, 0u);
      if (g2 < mm) kv = sCand[wv][g2];
      k[s] = kv.x; id[s] = kv.y;
    }
    // keys of d^2 >= 0 always have the top bit set -> start blo there
    unsigned blo = 0x80000000u, bhi = 0xFFFFFFFFu;   // bisect exact 64th-smallest key
    for (int it = 0; it < 32; ++it) {
      const unsigned mid = blo + ((bhi - blo) >> 1);
      const int c = (int)(__popcll(__ballot(k[0] <= mid)) + __popcll(__ballot(k[1] <= mid)) +
                          __popcll(__ballot(k[2] <= mid)) + __popcll(__ballot(k[3] <= mid)));
      if (c >= KNN) bhi = mid; else blo = mid + 1;
    }
    const unsigned K = blo;

    int fill = 0;
    #pragma unroll
    for (int s = 0; s < 4; ++s) {
      const bool lt = k[s] < K;
      const unsigned long long msk = __ballot(lt);
      if (msk) {
        const int p = fill + mbcnt64(msk);
        if (lt) { const float dv = val_of(k[s]);
                  const float w_ = 1.f / (sqrtf(fmaxf(dv, 1e-12f)) + 1e-5f);
                  sSel[wv][p] = make_uint2(id[s], __float_as_uint(w_)); }
        fill += (int)__popcll(msk);
      }
    }
    #pragma unroll
    for (int s = 0; s < 4; ++s) {          // ties at K fill remaining slots
      const bool eq = (k[s] == K);
      const unsigned long long msk = __ballot(eq);
      if (msk) {
        const int p = fill + mbcnt64(msk);
        if (eq && p < KNN) { const float dv = val_of(k[s]);
                             const float w_ = 1.f / (sqrtf(fmaxf(dv, 1e-12f)) + 1e-5f);
                             sSel[wv][p] = make_uint2(id[s], __float_as_uint(w_)); }
        fill += (int)__popcll(msk);
      }
    }
  }

  // ---- gather: float4/lane, halves split even/odd neighbors, 32 iterations ----
  {
    const int half = lane >> 5;            // 0: even j, 1: odd j
    const int col  = lane & 31;            // float4 column
    float4 acc = make_float4(0.f, 0.f, 0.f, 0.f);
    #pragma unroll 4
    for (int j = 0; j < KNN; j += 2) {
      const uint2 pr = sSel[wv][j + half];     // broadcast LDS read per half
      const float w = __uint_as_float(pr.y);
      const float4 f4 = *(const float4*)(feat + ((size_t)pr.x << 7) + (col << 2));
      acc.x = fmaf(w, f4.x, acc.x);
      acc.y = fmaf(w, f4.y, acc.y);
      acc.z = fmaf(w, f4.z, acc.z);
      acc.w = fmaf(w, f4.w, acc.w);
    }
    acc.x += __shfl_xor(acc.x, 32);
    acc.y += __shfl_xor(acc.y, 32);
    acc.z += __shfl_xor(acc.z, 32);
    acc.w += __shfl_xor(acc.w, 32);
    if (lane < 32)
      *(float4*)(out + ((size_t)orig << 7) + (col << 2)) = acc;
  }
}

extern "C" void kernel_launch(void* const* d_in, const int* in_sizes, int n_in,
                              void* d_out, int out_size, void* d_ws, size_t ws_size,
                              hipStream_t stream) {
  const float* qpos = (const float*)d_in[0];   // [8192,3]
  const float* feat = (const float*)d_in[1];   // [32768,128]
  const float* pos  = (const float*)d_in[2];   // [32768,3]
  float* out = (float*)d_out;                  // [8192,128]

  char* ws = (char*)d_ws;
  int*    pcnt      = (int*)(ws);                      // 1 MB   (point hist -> cursor)
  int*    qcnt      = (int*)(ws + (1024 << 10));       // 128 KB (query hist -> cursor)
  int*    ppub      = (int*)(ws + (1152 << 10));       // 1 KB (point chunk totals+1)
  int*    qpub      = (int*)(ws + (1153 << 10));       // 128 B (query chunk totals+1)
  int*    cellStart = (int*)(ws + (1156 << 10));       // 1 MB + 4 B (262145 ints)
  float*  tau       = (float*)(ws + (2188 << 10));     // 32 KB (by orig query idx)
  float4* pts       = (float4*)(ws + (2220 << 10));    // 512 KB (sorted points)
  float4* qp        = (float4*)(ws + (2732 << 10));    // 128 KB (sorted queries)
  float*  qtau      = (float*)(ws + (2860 << 10));     // 32 KB (sorted tau)

  hipMemsetAsync(ws, 0, 1154 << 10, stream);           // zero hists + publish flags
  hist_tau_kernel<<<dim3(NPTS / 256),        dim3(256), 0, stream>>>(pos, qpos, pcnt, qcnt, tau);
  scan_kernel    <<<dim3(PCHUNKS + QCHUNKS), dim3(256), 0, stream>>>(pcnt, qcnt, cellStart, ppub, qpub);
  scatter_kernel <<<dim3(NPTS / 256),        dim3(256), 0, stream>>>(pos, qpos, pcnt, qcnt, tau, pts, qp, qtau);
  knn_main       <<<dim3(NBLK),              dim3(256), 0, stream>>>(feat, cellStart, pts, qp, qtau, out);
}